// Round 1
// baseline (71.523 us; speedup 1.0000x reference)
//
#include <hip/hip_runtime.h>

// counts[b,t] = number of t' <= t with x[b,t'] == x[b,t].
// B*T^2/2 = 67M comparisons total; x row (16KB) staged in LDS.
// All lanes scan the same t' (uniform LDS address -> broadcast, no conflicts).

constexpr int B = 8;
constexpr int T = 4096;
constexpr int TILE = 256;   // t-positions per block; blockDim = TILE

__global__ __launch_bounds__(TILE) void prefix_count_kernel(
    const int* __restrict__ x, float* __restrict__ out) {
    const int tiles_per_batch = T / TILE;
    const int b = blockIdx.x / tiles_per_batch;
    const int tile = blockIdx.x % tiles_per_batch;
    const int end = (tile + 1) * TILE;   // scan prefix [0, end)

    __shared__ int sx[T];
    const int* xb = x + b * T;
    // stage x[b, 0..end) into LDS, coalesced
    for (int i = threadIdx.x; i < end; i += TILE) sx[i] = xb[i];
    __syncthreads();

    const int t = tile * TILE + threadIdx.x;
    const int tok = sx[t];
    int cnt = 0;
    // Uniform loop bound across the wave -> every lane reads the same LDS
    // address each iteration (broadcast). int4 read = ds_read_b128.
    #pragma unroll 4
    for (int tp = 0; tp < end; tp += 4) {
        const int4 v = *reinterpret_cast<const int4*>(&sx[tp]);
        cnt += (v.x == tok) & (tp + 0 <= t);
        cnt += (v.y == tok) & (tp + 1 <= t);
        cnt += (v.z == tok) & (tp + 2 <= t);
        cnt += (v.w == tok) & (tp + 3 <= t);
    }
    out[b * T + t] = (float)cnt;
}

extern "C" void kernel_launch(void* const* d_in, const int* in_sizes, int n_in,
                              void* d_out, int out_size, void* d_ws, size_t ws_size,
                              hipStream_t stream) {
    const int* x = (const int*)d_in[0];   // [B, T] int32 token ids
    // d_in[1] (one_hot, 256MB) intentionally unused.
    float* out = (float*)d_out;           // [B, T, 1] float32

    const int grid = B * (T / TILE);      // 128 blocks
    prefix_count_kernel<<<grid, TILE, 0, stream>>>(x, out);
}

// Round 2
// 18.195 us; speedup vs baseline: 3.9310x; 3.9310x over previous
//
#include <hip/hip_runtime.h>

// counts[b,t] = #{t' <= t : x[b,t'] == x[b,t]}
// Chunked-rank algorithm:
//   split each row into C chunks of CHUNK tokens;
//   K1: per-(b,c) histogram of chunk -> ws
//   K2: exclusive prefix-scan of histograms along c (in-place, per (b,v) column)
//   K3: count = scanned_hist[b][c][tok] + pairwise count within own chunk
// Work: ~B*T*(CHUNK/2) = 4.2M comparisons vs 67M brute force, fully balanced.

constexpr int B = 8;
constexpr int T = 4096;
constexpr int V = 2048;
constexpr int C = 16;          // chunks per row
constexpr int CHUNK = T / C;   // 256

// ---- K1: per-(b,chunk) histogram --------------------------------------
__global__ __launch_bounds__(CHUNK) void hist_kernel(const int* __restrict__ x,
                                                     int* __restrict__ hist) {
    const int b = blockIdx.x / C;
    const int c = blockIdx.x % C;
    __shared__ int h[V];
    for (int v = threadIdx.x; v < V; v += CHUNK) h[v] = 0;
    __syncthreads();
    const int tok = x[b * T + c * CHUNK + threadIdx.x];
    atomicAdd(&h[tok], 1);              // LDS atomic, ~no contention (256 adds / 2048 buckets)
    __syncthreads();
    int* o = hist + (b * C + c) * V;
    for (int v = threadIdx.x; v < V; v += CHUNK) o[v] = h[v];
}

// ---- K2: exclusive scan along c, in place (each thread owns one (b,v)) -
__global__ __launch_bounds__(256) void scan_kernel(int* __restrict__ hist) {
    const int idx = blockIdx.x * 256 + threadIdx.x;   // = b*V + v
    const int b = idx / V;
    const int v = idx - b * V;
    int* p = hist + b * C * V + v;
    int run = 0;
    #pragma unroll
    for (int c = 0; c < C; ++c) {
        const int h = p[c * V];
        p[c * V] = run;
        run += h;
    }
}

// ---- K3: final counts --------------------------------------------------
__global__ __launch_bounds__(CHUNK) void count_kernel(const int* __restrict__ x,
                                                      const int* __restrict__ cumhist,
                                                      float* __restrict__ out) {
    const int b = blockIdx.x / C;
    const int c = blockIdx.x % C;
    const int t0 = c * CHUNK;
    const int tid = (int)threadIdx.x;

    __shared__ int sx[CHUNK];
    sx[tid] = x[b * T + t0 + tid];
    __syncthreads();

    const int tok = sx[tid];
    int cnt = cumhist[(b * C + c) * V + tok];   // matches in all earlier chunks

    // pairwise scan within own chunk; uniform LDS address across lanes = broadcast
    #pragma unroll
    for (int tp = 0; tp < CHUNK; tp += 4) {
        const int4 w = *reinterpret_cast<const int4*>(&sx[tp]);
        cnt += (w.x == tok) & (tp + 0 <= tid);
        cnt += (w.y == tok) & (tp + 1 <= tid);
        cnt += (w.z == tok) & (tp + 2 <= tid);
        cnt += (w.w == tok) & (tp + 3 <= tid);
    }
    out[b * T + t0 + tid] = (float)cnt;
}

extern "C" void kernel_launch(void* const* d_in, const int* in_sizes, int n_in,
                              void* d_out, int out_size, void* d_ws, size_t ws_size,
                              hipStream_t stream) {
    const int* x = (const int*)d_in[0];   // [B, T] int32 token ids
    // d_in[1] (one_hot, 256MB) intentionally unused.
    float* out = (float*)d_out;           // [B, T, 1] float32
    int* hist = (int*)d_ws;               // B*C*V ints = 1 MB

    hist_kernel <<<B * C,        CHUNK, 0, stream>>>(x, hist);
    scan_kernel <<<B * V / 256,  256,   0, stream>>>(hist);
    count_kernel<<<B * C,        CHUNK, 0, stream>>>(x, hist, out);
}

// Round 3
// 11.786 us; speedup vs baseline: 6.0685x; 1.5438x over previous
//
#include <hip/hip_runtime.h>

// counts[b,t] = #{t' <= t : x[b,t'] == x[b,t]}
// Single fused kernel: block = one (batch, 256-token chunk).
//   phase 1: LDS-histogram the block's prefix x[b, 0..c*256)  (<=3840 atomics)
//   phase 2: count = hist[tok] + pairwise rank within own chunk
// x row (16KB) is L2-resident; total prefix re-reads ~1MB. No inter-kernel
// global round-trips, one graph node.

constexpr int B = 8;
constexpr int T = 4096;
constexpr int V = 2048;
constexpr int CHUNK = 256;
constexpr int C = T / CHUNK;   // 16

__global__ __launch_bounds__(CHUNK) void fused_count_kernel(
    const int* __restrict__ x, float* __restrict__ out) {
    const int b = blockIdx.x / C;
    const int c = blockIdx.x % C;
    const int t0 = c * CHUNK;
    const int tid = (int)threadIdx.x;

    __shared__ int hist[V];    // 8 KB
    __shared__ int sx[CHUNK];  // 1 KB

    #pragma unroll
    for (int v = tid; v < V; v += CHUNK) hist[v] = 0;
    const int* xb = x + b * T;
    sx[tid] = xb[t0 + tid];
    __syncthreads();

    // histogram the prefix [0, t0): coalesced int4 loads, LDS atomics
    // (random tokens over 2048 buckets -> ~no contention)
    for (int p = tid * 4; p < t0; p += CHUNK * 4) {
        const int4 w = *reinterpret_cast<const int4*>(&xb[p]);
        atomicAdd(&hist[w.x], 1);
        atomicAdd(&hist[w.y], 1);
        atomicAdd(&hist[w.z], 1);
        atomicAdd(&hist[w.w], 1);
    }
    __syncthreads();

    const int tok = sx[tid];
    int cnt = hist[tok];       // matches in all earlier chunks (0 for c==0)

    // pairwise rank within own chunk; uniform LDS address across lanes = broadcast
    #pragma unroll
    for (int tp = 0; tp < CHUNK; tp += 4) {
        const int4 w = *reinterpret_cast<const int4*>(&sx[tp]);
        cnt += (w.x == tok) & (tp + 0 <= tid);
        cnt += (w.y == tok) & (tp + 1 <= tid);
        cnt += (w.z == tok) & (tp + 2 <= tid);
        cnt += (w.w == tok) & (tp + 3 <= tid);
    }
    out[b * T + t0 + tid] = (float)cnt;
}

extern "C" void kernel_launch(void* const* d_in, const int* in_sizes, int n_in,
                              void* d_out, int out_size, void* d_ws, size_t ws_size,
                              hipStream_t stream) {
    const int* x = (const int*)d_in[0];   // [B, T] int32 token ids
    // d_in[1] (one_hot, 256MB) intentionally unused.
    float* out = (float*)d_out;           // [B, T, 1] float32

    fused_count_kernel<<<B * C, CHUNK, 0, stream>>>(x, out);
}

// Round 4
// 9.431 us; speedup vs baseline: 7.5840x; 1.2497x over previous
//
#include <hip/hip_runtime.h>

// counts[b,t] = #{t' <= t : x[b,t'] == x[b,t]}
// One WAVE per 64-token chunk (512 blocks x 64 threads).
//   phase 1: wave LDS-histograms its prefix x[b, 0..c*64)   (<=63 atomics/lane, pipelined)
//   phase 2: count = hist[tok] + rank within own 64-token chunk (16 ds_read_b128 iters)
// x row (16KB) is L2-resident; ~4MB total prefix re-reads absorbed by L2.
// Single graph node; kernel exec ~0.5us, remainder is launch/replay floor.

constexpr int B = 8;
constexpr int T = 4096;
constexpr int V = 2048;
constexpr int W = 64;          // chunk = one wave
constexpr int C = T / W;       // 64 chunks per row

__global__ __launch_bounds__(W) void fused_count_kernel(
    const int* __restrict__ x, float* __restrict__ out) {
    const int b = blockIdx.x / C;
    const int c = blockIdx.x % C;
    const int t0 = c * W;
    const int lane = (int)threadIdx.x;

    __shared__ int hist[V];    // 8 KB
    __shared__ int sx[W];

    // zero hist: 8 x ds_write_b128 per lane
    #pragma unroll
    for (int v = lane * 4; v < V; v += W * 4)
        *reinterpret_cast<int4*>(&hist[v]) = int4{0, 0, 0, 0};

    const int* xb = x + b * T;
    sx[lane] = xb[t0 + lane];
    __syncthreads();

    // histogram the prefix [0, t0): coalesced int4 loads (L2-hot), LDS atomics
    // (random tokens over 2048 buckets -> ~no contention, fully pipelined)
    for (int p = lane * 4; p < t0; p += W * 4) {
        const int4 w = *reinterpret_cast<const int4*>(&xb[p]);
        atomicAdd(&hist[w.x], 1);
        atomicAdd(&hist[w.y], 1);
        atomicAdd(&hist[w.z], 1);
        atomicAdd(&hist[w.w], 1);
    }
    __syncthreads();

    const int tok = sx[lane];
    int cnt = hist[tok];       // matches in all earlier chunks (0 for c==0)

    // rank within own 64-token chunk; uniform LDS address across lanes = broadcast
    #pragma unroll
    for (int tp = 0; tp < W; tp += 4) {
        const int4 w = *reinterpret_cast<const int4*>(&sx[tp]);
        cnt += (w.x == tok) & (tp + 0 <= lane);
        cnt += (w.y == tok) & (tp + 1 <= lane);
        cnt += (w.z == tok) & (tp + 2 <= lane);
        cnt += (w.w == tok) & (tp + 3 <= lane);
    }
    out[b * T + t0 + lane] = (float)cnt;
}

extern "C" void kernel_launch(void* const* d_in, const int* in_sizes, int n_in,
                              void* d_out, int out_size, void* d_ws, size_t ws_size,
                              hipStream_t stream) {
    const int* x = (const int*)d_in[0];   // [B, T] int32 token ids
    // d_in[1] (one_hot, 256MB) intentionally unused.
    float* out = (float*)d_out;           // [B, T, 1] float32

    fused_count_kernel<<<B * C, W, 0, stream>>>(x, out);
}

// Round 5
// 9.376 us; speedup vs baseline: 7.6283x; 1.0058x over previous
//
#include <hip/hip_runtime.h>

// counts[b,t] = #{t' <= t : x[b,t'] == x[b,t]}
// One WAVE per 64-token chunk (512 blocks x 64 threads).
//   phase 1: wave LDS-histograms its prefix x[b, 0..c*64)
//            -- loads batched 4-deep to hide L2 latency (~200cyc) on the
//               worst wave's 16-iteration chain
//   phase 2: count = hist[tok] + rank within own 64-token chunk
// Single graph node; exec ~1us, remainder is launch/replay floor.

constexpr int B = 8;
constexpr int T = 4096;
constexpr int V = 2048;
constexpr int W = 64;          // chunk = one wave
constexpr int C = T / W;       // 64 chunks per row

__global__ __launch_bounds__(W) void fused_count_kernel(
    const int* __restrict__ x, float* __restrict__ out) {
    const int b = blockIdx.x / C;
    const int c = blockIdx.x % C;
    const int t0 = c * W;
    const int lane = (int)threadIdx.x;

    __shared__ int hist[V];    // 8 KB
    __shared__ int sx[W];

    // zero hist: 8 x ds_write_b128 per lane
    #pragma unroll
    for (int v = lane * 4; v < V; v += W * 4)
        *reinterpret_cast<int4*>(&hist[v]) = int4{0, 0, 0, 0};

    const int* xb = x + b * T;
    sx[lane] = xb[t0 + lane];
    __syncthreads();

    // histogram the prefix [0, t0): 4-deep-batched int4 loads (L2-hot),
    // then 16 LDS atomics (random tokens over 2048 buckets -> ~no contention)
    const int stride = W * 4;  // 256 tokens per wave-iteration
    int p = lane * 4;
    while (p + 3 * stride < t0) {
        const int4 w0 = *reinterpret_cast<const int4*>(&xb[p]);
        const int4 w1 = *reinterpret_cast<const int4*>(&xb[p + stride]);
        const int4 w2 = *reinterpret_cast<const int4*>(&xb[p + 2 * stride]);
        const int4 w3 = *reinterpret_cast<const int4*>(&xb[p + 3 * stride]);
        atomicAdd(&hist[w0.x], 1); atomicAdd(&hist[w0.y], 1);
        atomicAdd(&hist[w0.z], 1); atomicAdd(&hist[w0.w], 1);
        atomicAdd(&hist[w1.x], 1); atomicAdd(&hist[w1.y], 1);
        atomicAdd(&hist[w1.z], 1); atomicAdd(&hist[w1.w], 1);
        atomicAdd(&hist[w2.x], 1); atomicAdd(&hist[w2.y], 1);
        atomicAdd(&hist[w2.z], 1); atomicAdd(&hist[w2.w], 1);
        atomicAdd(&hist[w3.x], 1); atomicAdd(&hist[w3.y], 1);
        atomicAdd(&hist[w3.z], 1); atomicAdd(&hist[w3.w], 1);
        p += 4 * stride;
    }
    while (p < t0) {
        const int4 w = *reinterpret_cast<const int4*>(&xb[p]);
        atomicAdd(&hist[w.x], 1); atomicAdd(&hist[w.y], 1);
        atomicAdd(&hist[w.z], 1); atomicAdd(&hist[w.w], 1);
        p += stride;
    }
    __syncthreads();

    const int tok = sx[lane];
    int cnt = hist[tok];       // matches in all earlier chunks (0 for c==0)

    // rank within own 64-token chunk; uniform LDS address across lanes = broadcast
    #pragma unroll
    for (int tp = 0; tp < W; tp += 4) {
        const int4 w = *reinterpret_cast<const int4*>(&sx[tp]);
        cnt += (w.x == tok) & (tp + 0 <= lane);
        cnt += (w.y == tok) & (tp + 1 <= lane);
        cnt += (w.z == tok) & (tp + 2 <= lane);
        cnt += (w.w == tok) & (tp + 3 <= lane);
    }
    out[b * T + t0 + lane] = (float)cnt;
}

extern "C" void kernel_launch(void* const* d_in, const int* in_sizes, int n_in,
                              void* d_out, int out_size, void* d_ws, size_t ws_size,
                              hipStream_t stream) {
    const int* x = (const int*)d_in[0];   // [B, T] int32 token ids
    // d_in[1] (one_hot, 256MB) intentionally unused.
    float* out = (float*)d_out;           // [B, T, 1] float32

    fused_count_kernel<<<B * C, W, 0, stream>>>(x, out);
}